// Round 3
// baseline (1397.796 us; speedup 1.0000x reference)
//
#include <hip/hip_runtime.h>
#include <stdint.h>

namespace {

constexpr int NN   = 100000;    // nodes
constexpr int NEDG = 1600000;   // edges
constexpr int NBAT = 512;       // graphs
constexpr int NSEG = 33;        // piecewise-linear segments of edge MLP (32 breakpoints)

// table layout (floats): bp[32] | d1[NSEG*32] | c1[NSEG*32] | per-enc {d2[NSEG*64], c2[NSEG*64]} x2
constexpr int TAB_BP = 0;
constexpr int TAB_D1 = 32;
constexpr int TAB_C1 = TAB_D1 + NSEG * 32;
constexpr int TAB_E2 = TAB_C1 + NSEG * 32;
constexpr int TAB_TOTAL = TAB_E2 + 4 * NSEG * 64;

__device__ __forceinline__ float relu_(float x) { return fmaxf(x, 0.0f); }

__device__ __forceinline__ float4 shfl_xor4(float4 v, int m) {
  return make_float4(__shfl_xor(v.x, m), __shfl_xor(v.y, m),
                     __shfl_xor(v.z, m), __shfl_xor(v.w, m));
}

// ---------------------------------------------------------------------------
// Precompute piecewise-linear tables for e(a) = relu(a*W1+b1)@W2+b2 and the
// folded e2(a) = e(a)@linW + linb. Exact reassociation of the reference math.
// ---------------------------------------------------------------------------
__global__ void build_tables(const float* __restrict__ eW1, const float* __restrict__ eb1,
                             const float* __restrict__ eW2, const float* __restrict__ eb2,
                             const float* __restrict__ sLW, const float* __restrict__ sLb,
                             const float* __restrict__ gLW, const float* __restrict__ gLb,
                             float* __restrict__ tabs) {
  __shared__ float traw[32];
  __shared__ float ts[32];
  __shared__ float dt[NSEG * 32];
  __shared__ float ct[NSEG * 32];
  int tid = threadIdx.x;
  if (tid < 32) {
    float w = eW1[tid], b = eb1[tid];
    traw[tid] = (w != 0.0f) ? (-b / w) : 3.0e38f;
  }
  __syncthreads();
  if (tid < 32) {  // rank sort (stable for duplicates)
    float v = traw[tid];
    int r = 0;
    for (int j = 0; j < 32; ++j) {
      float u = traw[j];
      r += (u < v) || (u == v && j < tid);
    }
    ts[r] = v;
  }
  __syncthreads();
  if (tid < 32) tabs[TAB_BP + tid] = ts[tid];
  for (int idx = tid; idx < NSEG * 32; idx += blockDim.x) {
    int s = idx >> 5, j = idx & 31;
    float a;  // representative point strictly inside segment s: (ts[s-1], ts[s]]
    if (s == 0)            a = ts[0] - 1.0f;
    else if (s == NSEG - 1) a = ts[31] + 1.0f;
    else                   a = 0.5f * ts[s - 1] + 0.5f * ts[s];
    float d = 0.0f, c = 0.0f;
    for (int i = 0; i < 32; ++i) {
      float w = eW1[i], b = eb1[i];
      if (fmaf(a, w, b) > 0.0f) {
        float w2 = eW2[i * 32 + j];
        d = fmaf(w, w2, d);
        c = fmaf(b, w2, c);
      }
    }
    c += eb2[j];
    dt[idx] = d; ct[idx] = c;
    tabs[TAB_D1 + idx] = d;
    tabs[TAB_C1 + idx] = c;
  }
  __syncthreads();
  for (int idx = tid; idx < NSEG * 64; idx += blockDim.x) {
    int s = idx >> 6, k = idx & 63;
    float ds = 0.f, cs = 0.f, dg = 0.f, cg = 0.f;
    for (int j = 0; j < 32; ++j) {
      float dv = dt[s * 32 + j], cv = ct[s * 32 + j];
      float ws = sLW[j * 64 + k], wg = gLW[j * 64 + k];
      ds = fmaf(dv, ws, ds); cs = fmaf(cv, ws, cs);
      dg = fmaf(dv, wg, dg); cg = fmaf(cv, wg, cg);
    }
    cs += sLb[k]; cg += gLb[k];
    tabs[TAB_E2 + idx]                 = ds;
    tabs[TAB_E2 + NSEG * 64 + idx]     = cs;
    tabs[TAB_E2 + 2 * NSEG * 64 + idx] = dg;
    tabs[TAB_E2 + 3 * NSEG * 64 + idx] = cg;
  }
}

// ---------------------------------------------------------------------------
// x0[n,32] = MLP2(clip((names+2)/SCALE,0,1))
// ---------------------------------------------------------------------------
__global__ __launch_bounds__(256) void node_embed(
    const int* __restrict__ names,
    const float* __restrict__ W1, const float* __restrict__ b1,
    const float* __restrict__ W2, const float* __restrict__ b2,
    float* __restrict__ x0) {
  int n = blockIdx.x * 256 + threadIdx.x;
  if (n >= NN) return;
  float norm = ((float)names[n] + 2.0f) / 281474976710655.0f;
  norm = fminf(fmaxf(norm, 0.0f), 1.0f);
  float h[32];
#pragma unroll
  for (int i = 0; i < 32; ++i) h[i] = relu_(fmaf(norm, W1[i], b1[i]));
  float4* out = (float4*)(x0 + (size_t)n * 32);
  for (int j0 = 0; j0 < 32; j0 += 4) {
    float a0 = b2[j0], a1 = b2[j0 + 1], a2 = b2[j0 + 2], a3 = b2[j0 + 3];
#pragma unroll
    for (int i = 0; i < 32; ++i) {
      float hv = h[i];
      a0 = fmaf(hv, W2[i * 32 + j0],     a0);
      a1 = fmaf(hv, W2[i * 32 + j0 + 1], a1);
      a2 = fmaf(hv, W2[i * 32 + j0 + 2], a2);
      a3 = fmaf(hv, W2[i * 32 + j0 + 3], a3);
    }
    out[j0 >> 2] = make_float4(a0, a1, a2, a3);
  }
}

// ---------------------------------------------------------------------------
// CSR-by-dst build: histogram -> scan -> fill (seg id packed into src word)
// hist/fill process 4 edges per thread: 4 independent atomics/stores in
// flight per thread (latency-bound fix).
// ---------------------------------------------------------------------------
__global__ __launch_bounds__(256) void hist_dst(const int* __restrict__ dst, int* __restrict__ cnt) {
  int e0 = (blockIdx.x * 256 + threadIdx.x) * 4;
  if (e0 >= NEDG) return;  // NEDG % 4 == 0 -> whole quad valid
  int4 d4 = *(const int4*)(dst + e0);
  atomicAdd(&cnt[d4.x], 1);
  atomicAdd(&cnt[d4.y], 1);
  atomicAdd(&cnt[d4.z], 1);
  atomicAdd(&cnt[d4.w], 1);
}

__global__ __launch_bounds__(256) void block_sums(const int* __restrict__ cnt, int* __restrict__ bsum, int n) {
  __shared__ int s[256];
  int i = blockIdx.x * 256 + threadIdx.x;
  s[threadIdx.x] = (i < n) ? cnt[i] : 0;
  __syncthreads();
  for (int st = 128; st > 0; st >>= 1) {
    if ((int)threadIdx.x < st) s[threadIdx.x] += s[threadIdx.x + st];
    __syncthreads();
  }
  if (threadIdx.x == 0) bsum[blockIdx.x] = s[0];
}

__global__ __launch_bounds__(512) void scan_partials(int* __restrict__ bsum, int nb) {
  __shared__ int s[512];
  int v = ((int)threadIdx.x < nb) ? bsum[threadIdx.x] : 0;
  s[threadIdx.x] = v;
  __syncthreads();
  for (int st = 1; st < 512; st <<= 1) {
    int t = ((int)threadIdx.x >= st) ? s[threadIdx.x - st] : 0;
    __syncthreads();
    s[threadIdx.x] += t;
    __syncthreads();
  }
  if ((int)threadIdx.x < nb) bsum[threadIdx.x] = s[threadIdx.x] - v;  // exclusive
}

__global__ __launch_bounds__(256) void write_rowptr(
    const int* __restrict__ cnt, const int* __restrict__ bsum,
    int* __restrict__ rowptr, int* __restrict__ wp, int n, int total) {
  __shared__ int s[256];
  int i = blockIdx.x * 256 + threadIdx.x;
  int v = (i < n) ? cnt[i] : 0;
  s[threadIdx.x] = v;
  __syncthreads();
  for (int st = 1; st < 256; st <<= 1) {
    int t = ((int)threadIdx.x >= st) ? s[threadIdx.x - st] : 0;
    __syncthreads();
    s[threadIdx.x] += t;
    __syncthreads();
  }
  int excl = s[threadIdx.x] - v + bsum[blockIdx.x];
  if (i < n) { rowptr[i] = excl; wp[i] = excl; }
  if (i == n - 1) rowptr[n] = total;
}

__global__ __launch_bounds__(256) void csr_fill(
    const int* __restrict__ src, const int* __restrict__ dst,
    const float* __restrict__ attr, const float* __restrict__ tabs,
    int* __restrict__ wp, int2* __restrict__ colattr) {
  __shared__ float bp[32];
  if (threadIdx.x < 32) bp[threadIdx.x] = tabs[TAB_BP + threadIdx.x];
  __syncthreads();
  int e0 = (blockIdx.x * 256 + threadIdx.x) * 4;
  if (e0 >= NEDG) return;  // NEDG % 4 == 0 -> whole quad valid
  int4   d4 = *(const int4*)(dst + e0);
  int4   s4 = *(const int4*)(src + e0);
  float4 a4 = *(const float4*)(attr + e0);
  // seg = #(bp < a), unrolled compare against LDS-broadcast breakpoints
  int g0 = 0, g1 = 0, g2 = 0, g3 = 0;
#pragma unroll
  for (int i = 0; i < 32; ++i) {
    float b = bp[i];
    g0 += (b < a4.x); g1 += (b < a4.y); g2 += (b < a4.z); g3 += (b < a4.w);
  }
  int p0 = atomicAdd(&wp[d4.x], 1);
  int p1 = atomicAdd(&wp[d4.y], 1);
  int p2 = atomicAdd(&wp[d4.z], 1);
  int p3 = atomicAdd(&wp[d4.w], 1);
  colattr[p0] = make_int2(s4.x | (g0 << 20), __float_as_int(a4.x));  // src<2^17, seg<64
  colattr[p1] = make_int2(s4.y | (g1 << 20), __float_as_int(a4.y));
  colattr[p2] = make_int2(s4.z | (g2 << 20), __float_as_int(a4.z));
  colattr[p3] = make_int2(s4.w | (g3 << 20), __float_as_int(a4.w));
}

// ---------------------------------------------------------------------------
// GINE aggregation, dst-major. One WAVE per node; a wave processes several
// edges concurrently (sub = edge slot, fq = float4 feature chunk) so 8-16 row
// gathers are in flight per wave (latency-bound fix).
// hb[n] = x[n] + sum_j relu(x[src_j] + e_j)
// ---------------------------------------------------------------------------
__global__ __launch_bounds__(256) void conv1_agg(
    const float* __restrict__ x0, const int* __restrict__ rowptr,
    const int2* __restrict__ colattr, const float* __restrict__ tabs,
    float* __restrict__ hb) {
  __shared__ float dt[NSEG * 32];
  __shared__ float ct[NSEG * 32];
  for (int i = threadIdx.x; i < NSEG * 32; i += 256) {
    dt[i] = tabs[TAB_D1 + i];
    ct[i] = tabs[TAB_C1 + i];
  }
  __syncthreads();
  int n = blockIdx.x * 4 + (threadIdx.x >> 6);  // grid exact: NN/4
  int lane = threadIdx.x & 63;
  int sub = lane & 7;        // 8 edges in flight (x2 unroll = 16)
  int fq  = lane >> 3;       // 8 float4 chunks -> 32 features
  int f0  = fq * 4;
  int beg = rowptr[n], end = rowptr[n + 1];
  float4 acc = make_float4(0.f, 0.f, 0.f, 0.f);
  for (int k = beg + sub; k < end; k += 16) {
    int2 ca0 = colattr[k];
    int kb = k + 8;
    bool h1 = kb < end;
    int2 ca1 = h1 ? colattr[kb] : ca0;
    unsigned p0 = (unsigned)ca0.x, p1 = (unsigned)ca1.x;
    int s0 = (int)(p0 & 0xFFFFFu), g0 = (int)(p0 >> 20);
    int s1 = (int)(p1 & 0xFFFFFu), g1 = (int)(p1 >> 20);
    float a0 = __int_as_float(ca0.y), a1 = __int_as_float(ca1.y);
    float4 xv0 = *(const float4*)(x0 + (size_t)s0 * 32 + f0);
    float4 xv1 = *(const float4*)(x0 + (size_t)s1 * 32 + f0);
    float4 d0 = *(const float4*)&dt[g0 * 32 + f0];
    float4 c0 = *(const float4*)&ct[g0 * 32 + f0];
    float4 d1 = *(const float4*)&dt[g1 * 32 + f0];
    float4 c1 = *(const float4*)&ct[g1 * 32 + f0];
    acc.x += relu_(xv0.x + fmaf(a0, d0.x, c0.x));
    acc.y += relu_(xv0.y + fmaf(a0, d0.y, c0.y));
    acc.z += relu_(xv0.z + fmaf(a0, d0.z, c0.z));
    acc.w += relu_(xv0.w + fmaf(a0, d0.w, c0.w));
    if (h1) {
      acc.x += relu_(xv1.x + fmaf(a1, d1.x, c1.x));
      acc.y += relu_(xv1.y + fmaf(a1, d1.y, c1.y));
      acc.z += relu_(xv1.z + fmaf(a1, d1.z, c1.z));
      acc.w += relu_(xv1.w + fmaf(a1, d1.w, c1.w));
    }
  }
#pragma unroll
  for (int m = 1; m < 8; m <<= 1) {
    float4 o = shfl_xor4(acc, m);
    acc.x += o.x; acc.y += o.y; acc.z += o.z; acc.w += o.w;
  }
  if (sub == 0) {
    const float4 self = *(const float4*)(x0 + (size_t)n * 32 + f0);
    *(float4*)(hb + (size_t)n * 32 + f0) =
        make_float4(self.x + acc.x, self.y + acc.y, self.z + acc.z, self.w + acc.w);
  }
}

__global__ __launch_bounds__(256) void conv2_agg(
    const float* __restrict__ x1, const int* __restrict__ rowptr,
    const int2* __restrict__ colattr, const float* __restrict__ tabs, int enc,
    float* __restrict__ hb) {
  __shared__ float dt[NSEG * 64];
  __shared__ float ct[NSEG * 64];
  const float* d2 = tabs + TAB_E2 + (size_t)enc * 2 * NSEG * 64;
  for (int i = threadIdx.x; i < NSEG * 64; i += 256) {
    dt[i] = d2[i];
    ct[i] = d2[NSEG * 64 + i];
  }
  __syncthreads();
  int n = blockIdx.x * 4 + (threadIdx.x >> 6);  // grid exact: NN/4
  int lane = threadIdx.x & 63;
  int sub = lane & 3;        // 4 edges in flight (x2 unroll = 8)
  int fq  = lane >> 2;       // 16 float4 chunks -> 64 features
  int f0  = fq * 4;
  int beg = rowptr[n], end = rowptr[n + 1];
  float4 acc = make_float4(0.f, 0.f, 0.f, 0.f);
  for (int k = beg + sub; k < end; k += 8) {
    int2 ca0 = colattr[k];
    int kb = k + 4;
    bool h1 = kb < end;
    int2 ca1 = h1 ? colattr[kb] : ca0;
    unsigned p0 = (unsigned)ca0.x, p1 = (unsigned)ca1.x;
    int s0 = (int)(p0 & 0xFFFFFu), g0 = (int)(p0 >> 20);
    int s1 = (int)(p1 & 0xFFFFFu), g1 = (int)(p1 >> 20);
    float a0 = __int_as_float(ca0.y), a1 = __int_as_float(ca1.y);
    float4 xv0 = *(const float4*)(x1 + (size_t)s0 * 64 + f0);
    float4 xv1 = *(const float4*)(x1 + (size_t)s1 * 64 + f0);
    float4 d0 = *(const float4*)&dt[g0 * 64 + f0];
    float4 c0 = *(const float4*)&ct[g0 * 64 + f0];
    float4 d1 = *(const float4*)&dt[g1 * 64 + f0];
    float4 c1 = *(const float4*)&ct[g1 * 64 + f0];
    acc.x += relu_(xv0.x + fmaf(a0, d0.x, c0.x));
    acc.y += relu_(xv0.y + fmaf(a0, d0.y, c0.y));
    acc.z += relu_(xv0.z + fmaf(a0, d0.z, c0.z));
    acc.w += relu_(xv0.w + fmaf(a0, d0.w, c0.w));
    if (h1) {
      acc.x += relu_(xv1.x + fmaf(a1, d1.x, c1.x));
      acc.y += relu_(xv1.y + fmaf(a1, d1.y, c1.y));
      acc.z += relu_(xv1.z + fmaf(a1, d1.z, c1.z));
      acc.w += relu_(xv1.w + fmaf(a1, d1.w, c1.w));
    }
  }
#pragma unroll
  for (int m = 1; m < 4; m <<= 1) {
    float4 o = shfl_xor4(acc, m);
    acc.x += o.x; acc.y += o.y; acc.z += o.z; acc.w += o.w;
  }
  if (sub == 0) {
    const float4 self = *(const float4*)(x1 + (size_t)n * 64 + f0);
    *(float4*)(hb + (size_t)n * 64 + f0) =
        make_float4(self.x + acc.x, self.y + acc.y, self.z + acc.z, self.w + acc.w);
  }
}

// ---------------------------------------------------------------------------
// Per-node MLP2 (IN -> 64 -> 64), relu on output (conv wrapper relu).
// ---------------------------------------------------------------------------
template <int IN, int TPB>
__global__ __launch_bounds__(TPB) void node_mlp(
    const float* __restrict__ hin,
    const float* __restrict__ W1, const float* __restrict__ b1,
    const float* __restrict__ W2, const float* __restrict__ b2,
    float* __restrict__ xout) {
  __shared__ float hs[TPB][IN + 1];
  int base = blockIdx.x * TPB;
  int count = NN - base; if (count > TPB) count = TPB;
  for (int i = threadIdx.x; i < count * IN; i += TPB) {
    int ln = i / IN, k = i - ln * IN;
    hs[ln][k] = hin[(size_t)(base + ln) * IN + k];
  }
  __syncthreads();
  int n = base + threadIdx.x;
  if (n >= NN) return;
  float y[64];
#pragma unroll
  for (int f = 0; f < 64; ++f) y[f] = b1[f];
  for (int k = 0; k < IN; ++k) {
    float hv = hs[threadIdx.x][k];
#pragma unroll
    for (int f = 0; f < 64; ++f) y[f] = fmaf(hv, W1[k * 64 + f], y[f]);
  }
#pragma unroll
  for (int f = 0; f < 64; ++f) y[f] = relu_(y[f]);
  float4* out = (float4*)(xout + (size_t)n * 64);
  for (int f0 = 0; f0 < 64; f0 += 4) {
    float a0 = b2[f0], a1 = b2[f0 + 1], a2 = b2[f0 + 2], a3 = b2[f0 + 3];
#pragma unroll
    for (int k = 0; k < 64; ++k) {
      float yv = y[k];
      a0 = fmaf(yv, W2[k * 64 + f0],     a0);
      a1 = fmaf(yv, W2[k * 64 + f0 + 1], a1);
      a2 = fmaf(yv, W2[k * 64 + f0 + 2], a2);
      a3 = fmaf(yv, W2[k * 64 + f0 + 3], a3);
    }
    out[f0 >> 2] = make_float4(relu_(a0), relu_(a1), relu_(a2), relu_(a3));
  }
}

// ---------------------------------------------------------------------------
// global mean pool (batch is sorted -> contiguous node ranges per graph)
// ---------------------------------------------------------------------------
__global__ __launch_bounds__(256) void hist_batch(const int* __restrict__ bat, int* __restrict__ bcnt) {
  int i = blockIdx.x * 256 + threadIdx.x;
  if (i < NN) atomicAdd(&bcnt[bat[i]], 1);
}

__global__ __launch_bounds__(512) void batch_rowptr(const int* __restrict__ bcnt, int* __restrict__ brow) {
  __shared__ int s[512];
  int v = bcnt[threadIdx.x];
  s[threadIdx.x] = v;
  __syncthreads();
  for (int st = 1; st < 512; st <<= 1) {
    int t = ((int)threadIdx.x >= st) ? s[threadIdx.x - st] : 0;
    __syncthreads();
    s[threadIdx.x] += t;
    __syncthreads();
  }
  if (threadIdx.x == 0) brow[0] = 0;
  brow[threadIdx.x + 1] = s[threadIdx.x];
}

__global__ __launch_bounds__(256) void pool_mean(
    const float* __restrict__ x2, const int* __restrict__ brow, float* __restrict__ pool) {
  __shared__ float s[4][64];
  int g = blockIdx.x;
  int f = threadIdx.x & 63, c = threadIdx.x >> 6;
  int beg = brow[g], end = brow[g + 1];
  float acc = 0.0f;
  for (int n = beg + c; n < end; n += 4) acc += x2[(size_t)n * 64 + f];
  s[c][f] = acc;
  __syncthreads();
  if (c == 0) {
    float tot = s[0][f] + s[1][f] + s[2][f] + s[3][f];
    float m = (float)(end - beg);
    pool[g * 64 + f] = tot / fmaxf(m, 1.0f);
  }
}

// ---------------------------------------------------------------------------
// regressor: out[b] = relu([s|g|depth] @ rW1 + rb1) @ rW2 + rb2
// ---------------------------------------------------------------------------
__global__ __launch_bounds__(256) void regressor(
    const float* __restrict__ ps, const float* __restrict__ pg, const float* __restrict__ depth,
    const float* __restrict__ W1, const float* __restrict__ b1,
    const float* __restrict__ W2, const float* __restrict__ b2,
    float* __restrict__ out) {
  int b = blockIdx.x * 256 + threadIdx.x;  // grid 2x256 = 512 exact
  float y[64];
#pragma unroll
  for (int f = 0; f < 64; ++f) y[f] = b1[f];
  for (int k = 0; k < 64; ++k) {
    float zv = ps[(size_t)b * 64 + k];
#pragma unroll
    for (int f = 0; f < 64; ++f) y[f] = fmaf(zv, W1[k * 64 + f], y[f]);
  }
  for (int k = 0; k < 64; ++k) {
    float zv = pg[(size_t)b * 64 + k];
#pragma unroll
    for (int f = 0; f < 64; ++f) y[f] = fmaf(zv, W1[(64 + k) * 64 + f], y[f]);
  }
  {
    float zv = depth[b];
#pragma unroll
    for (int f = 0; f < 64; ++f) y[f] = fmaf(zv, W1[128 * 64 + f], y[f]);
  }
  float acc = b2[0];
#pragma unroll
  for (int f = 0; f < 64; ++f) acc = fmaf(relu_(y[f]), W2[f], acc);
  out[b] = acc;
}

}  // namespace

extern "C" void kernel_launch(void* const* d_in, const int* in_sizes, int n_in,
                              void* d_out, int out_size, void* d_ws, size_t ws_size,
                              hipStream_t stream) {
  const int*   names_s = (const int*)d_in[0];
  const int*   ei_s    = (const int*)d_in[1];
  const float* ea_s    = (const float*)d_in[2];
  const int*   bat_s   = (const int*)d_in[3];
  const int*   names_g = (const int*)d_in[4];
  const int*   ei_g    = (const int*)d_in[5];
  const float* ea_g    = (const float*)d_in[6];
  const int*   bat_g   = (const int*)d_in[7];
  const float* depth   = (const float*)d_in[8];
  const float* idW1 = (const float*)d_in[9],  *idb1 = (const float*)d_in[10];
  const float* idW2 = (const float*)d_in[11], *idb2 = (const float*)d_in[12];
  const float* edW1 = (const float*)d_in[13], *edb1 = (const float*)d_in[14];
  const float* edW2 = (const float*)d_in[15], *edb2 = (const float*)d_in[16];
  const float* s1W1 = (const float*)d_in[17], *s1b1 = (const float*)d_in[18];
  const float* s1W2 = (const float*)d_in[19], *s1b2 = (const float*)d_in[20];
  const float* s2W1 = (const float*)d_in[21], *s2b1 = (const float*)d_in[22];
  const float* s2W2 = (const float*)d_in[23], *s2b2 = (const float*)d_in[24];
  const float* s2LW = (const float*)d_in[25], *s2Lb = (const float*)d_in[26];
  const float* g1W1 = (const float*)d_in[27], *g1b1 = (const float*)d_in[28];
  const float* g1W2 = (const float*)d_in[29], *g1b2 = (const float*)d_in[30];
  const float* g2W1 = (const float*)d_in[31], *g2b1 = (const float*)d_in[32];
  const float* g2W2 = (const float*)d_in[33], *g2b2 = (const float*)d_in[34];
  const float* g2LW = (const float*)d_in[35], *g2Lb = (const float*)d_in[36];
  const float* rW1  = (const float*)d_in[37], *rb1  = (const float*)d_in[38];
  const float* rW2  = (const float*)d_in[39], *rb2  = (const float*)d_in[40];
  (void)in_sizes; (void)n_in; (void)out_size; (void)ws_size;

  char* ws = (char*)d_ws;
  size_t off = 0;
  auto alloc = [&](size_t bytes) -> char* {
    char* p = ws + off;
    off += (bytes + 255) & ~(size_t)255;
    return p;
  };
  float* tabs    = (float*)alloc((size_t)TAB_TOTAL * 4);
  float* bufA    = (float*)alloc((size_t)NN * 64 * 4);   // x0 -> x1 -> x2
  float* bufB    = (float*)alloc((size_t)NN * 64 * 4);   // h1 -> h2
  int2*  colattr = (int2*) alloc((size_t)NEDG * 8);
  int*   cnt     = (int*)  alloc((size_t)NN * 4);
  int*   rowptr  = (int*)  alloc((size_t)(NN + 1) * 4);
  int*   wp      = (int*)  alloc((size_t)NN * 4);
  int*   bsum    = (int*)  alloc(512 * 4);
  int*   bcnt    = (int*)  alloc((size_t)NBAT * 4);
  int*   brow    = (int*)  alloc((size_t)(NBAT + 1) * 4);
  float* pool_s  = (float*)alloc((size_t)NBAT * 64 * 4);
  float* pool_g  = (float*)alloc((size_t)NBAT * 64 * 4);

  build_tables<<<1, 256, 0, stream>>>(edW1, edb1, edW2, edb2, s2LW, s2Lb, g2LW, g2Lb, tabs);

  auto encoder = [&](const int* names, const int* ei, const float* ea, const int* bat,
                     const float* c1W1, const float* c1b1, const float* c1W2, const float* c1b2,
                     const float* c2W1, const float* c2b1, const float* c2W2, const float* c2b2,
                     int enc, float* pool) {
    const int* src = ei;
    const int* dst = ei + NEDG;
    node_embed<<<391, 256, 0, stream>>>(names, idW1, idb1, idW2, idb2, bufA);
    hipMemsetAsync(cnt, 0, (size_t)NN * 4, stream);
    hist_dst<<<(NEDG + 1023) / 1024, 256, 0, stream>>>(dst, cnt);
    block_sums<<<391, 256, 0, stream>>>(cnt, bsum, NN);
    scan_partials<<<1, 512, 0, stream>>>(bsum, 391);
    write_rowptr<<<391, 256, 0, stream>>>(cnt, bsum, rowptr, wp, NN, NEDG);
    csr_fill<<<(NEDG + 1023) / 1024, 256, 0, stream>>>(src, dst, ea, tabs, wp, colattr);
    conv1_agg<<<NN / 4, 256, 0, stream>>>(bufA, rowptr, colattr, tabs, bufB);
    node_mlp<32, 256><<<(NN + 255) / 256, 256, 0, stream>>>(bufB, c1W1, c1b1, c1W2, c1b2, bufA);
    conv2_agg<<<NN / 4, 256, 0, stream>>>(bufA, rowptr, colattr, tabs, enc, bufB);
    node_mlp<64, 128><<<(NN + 127) / 128, 128, 0, stream>>>(bufB, c2W1, c2b1, c2W2, c2b2, bufA);
    hipMemsetAsync(bcnt, 0, (size_t)NBAT * 4, stream);
    hist_batch<<<391, 256, 0, stream>>>(bat, bcnt);
    batch_rowptr<<<1, 512, 0, stream>>>(bcnt, brow);
    pool_mean<<<NBAT, 256, 0, stream>>>(bufA, brow, pool);
  };

  encoder(names_s, ei_s, ea_s, bat_s, s1W1, s1b1, s1W2, s1b2, s2W1, s2b1, s2W2, s2b2, 0, pool_s);
  encoder(names_g, ei_g, ea_g, bat_g, g1W1, g1b1, g1W2, g1b2, g2W1, g2b1, g2W2, g2b2, 1, pool_g);

  regressor<<<2, 256, 0, stream>>>(pool_s, pool_g, depth, rW1, rb1, rW2, rb2, (float*)d_out);
}

// Round 4
// 1349.633 us; speedup vs baseline: 1.0357x; 1.0357x over previous
//
#include <hip/hip_runtime.h>
#include <stdint.h>

namespace {

constexpr int NN   = 100000;    // nodes per graph
constexpr int NEDG = 1600000;   // edges per graph
constexpr int NBAT = 512;       // graphs per batch
constexpr int NSEG = 33;        // piecewise-linear segments of edge MLP (32 breakpoints)
constexpr int EBLK = NEDG / 256;  // 6250 blocks per graph for edge kernels

// table layout (floats): bp[32] | d1[NSEG*32] | c1[NSEG*32] | per-enc {d2[NSEG*64], c2[NSEG*64]} x2
constexpr int TAB_BP = 0;
constexpr int TAB_D1 = 32;
constexpr int TAB_C1 = TAB_D1 + NSEG * 32;
constexpr int TAB_E2 = TAB_C1 + NSEG * 32;
constexpr int TAB_TOTAL = TAB_E2 + 4 * NSEG * 64;

__device__ __forceinline__ float relu_(float x) { return fmaxf(x, 0.0f); }

__device__ __forceinline__ float4 shfl_xor4(float4 v, int m) {
  return make_float4(__shfl_xor(v.x, m), __shfl_xor(v.y, m),
                     __shfl_xor(v.z, m), __shfl_xor(v.w, m));
}

// ---------------------------------------------------------------------------
// Precompute piecewise-linear tables for e(a) = relu(a*W1+b1)@W2+b2 and the
// folded e2(a) = e(a)@linW + linb. Exact reassociation of the reference math.
// ---------------------------------------------------------------------------
__global__ void build_tables(const float* __restrict__ eW1, const float* __restrict__ eb1,
                             const float* __restrict__ eW2, const float* __restrict__ eb2,
                             const float* __restrict__ sLW, const float* __restrict__ sLb,
                             const float* __restrict__ gLW, const float* __restrict__ gLb,
                             float* __restrict__ tabs) {
  __shared__ float traw[32];
  __shared__ float ts[32];
  __shared__ float dt[NSEG * 32];
  __shared__ float ct[NSEG * 32];
  int tid = threadIdx.x;
  if (tid < 32) {
    float w = eW1[tid], b = eb1[tid];
    traw[tid] = (w != 0.0f) ? (-b / w) : 3.0e38f;
  }
  __syncthreads();
  if (tid < 32) {  // rank sort (stable for duplicates)
    float v = traw[tid];
    int r = 0;
    for (int j = 0; j < 32; ++j) {
      float u = traw[j];
      r += (u < v) || (u == v && j < tid);
    }
    ts[r] = v;
  }
  __syncthreads();
  if (tid < 32) tabs[TAB_BP + tid] = ts[tid];
  for (int idx = tid; idx < NSEG * 32; idx += blockDim.x) {
    int s = idx >> 5, j = idx & 31;
    float a;  // representative point strictly inside segment s: (ts[s-1], ts[s]]
    if (s == 0)            a = ts[0] - 1.0f;
    else if (s == NSEG - 1) a = ts[31] + 1.0f;
    else                   a = 0.5f * ts[s - 1] + 0.5f * ts[s];
    float d = 0.0f, c = 0.0f;
    for (int i = 0; i < 32; ++i) {
      float w = eW1[i], b = eb1[i];
      if (fmaf(a, w, b) > 0.0f) {
        float w2 = eW2[i * 32 + j];
        d = fmaf(w, w2, d);
        c = fmaf(b, w2, c);
      }
    }
    c += eb2[j];
    dt[idx] = d; ct[idx] = c;
    tabs[TAB_D1 + idx] = d;
    tabs[TAB_C1 + idx] = c;
  }
  __syncthreads();
  for (int idx = tid; idx < NSEG * 64; idx += blockDim.x) {
    int s = idx >> 6, k = idx & 63;
    float ds = 0.f, cs = 0.f, dg = 0.f, cg = 0.f;
    for (int j = 0; j < 32; ++j) {
      float dv = dt[s * 32 + j], cv = ct[s * 32 + j];
      float ws = sLW[j * 64 + k], wg = gLW[j * 64 + k];
      ds = fmaf(dv, ws, ds); cs = fmaf(cv, ws, cs);
      dg = fmaf(dv, wg, dg); cg = fmaf(cv, wg, cg);
    }
    cs += sLb[k]; cg += gLb[k];
    tabs[TAB_E2 + idx]                 = ds;
    tabs[TAB_E2 + NSEG * 64 + idx]     = cs;
    tabs[TAB_E2 + 2 * NSEG * 64 + idx] = dg;
    tabs[TAB_E2 + 3 * NSEG * 64 + idx] = cg;
  }
}

// ---------------------------------------------------------------------------
// x0[n,32] = MLP2(clip((names+2)/SCALE,0,1))
// ---------------------------------------------------------------------------
__global__ __launch_bounds__(256, 2) void node_embed(
    const int* __restrict__ names,
    const float* __restrict__ W1, const float* __restrict__ b1,
    const float* __restrict__ W2, const float* __restrict__ b2,
    float* __restrict__ x0) {
  int n = blockIdx.x * 256 + threadIdx.x;
  if (n >= NN) return;
  float norm = ((float)names[n] + 2.0f) / 281474976710655.0f;
  norm = fminf(fmaxf(norm, 0.0f), 1.0f);
  float h[32];
#pragma unroll
  for (int i = 0; i < 32; ++i) h[i] = relu_(fmaf(norm, W1[i], b1[i]));
  float4* out = (float4*)(x0 + (size_t)n * 32);
  for (int j0 = 0; j0 < 32; j0 += 4) {
    float a0 = b2[j0], a1 = b2[j0 + 1], a2 = b2[j0 + 2], a3 = b2[j0 + 3];
#pragma unroll
    for (int i = 0; i < 32; ++i) {
      float hv = h[i];
      a0 = fmaf(hv, W2[i * 32 + j0],     a0);
      a1 = fmaf(hv, W2[i * 32 + j0 + 1], a1);
      a2 = fmaf(hv, W2[i * 32 + j0 + 2], a2);
      a3 = fmaf(hv, W2[i * 32 + j0 + 3], a3);
    }
    out[j0 >> 2] = make_float4(a0, a1, a2, a3);
  }
}

// ---------------------------------------------------------------------------
// Dual-graph CSR-by-dst build: both graphs' histograms/fills in ONE launch
// (the s/g pipelines are independent; merging doubles the in-flight atomics
// for these latency-bound kernels). Graph-g node bins are offset by NN.
// Blocks [0,EBLK) -> graph s, [EBLK,2*EBLK) -> graph g (wave-uniform half).
// ---------------------------------------------------------------------------
__global__ __launch_bounds__(256) void hist_dst_dual(
    const int* __restrict__ dst_s, const int* __restrict__ dst_g,
    int* __restrict__ cnt) {
  int half = blockIdx.x >= EBLK;
  int e = (blockIdx.x - half * EBLK) * 256 + threadIdx.x;  // exact
  int d = half ? (dst_g[e] + NN) : dst_s[e];
  atomicAdd(&cnt[d], 1);
}

__global__ __launch_bounds__(256) void block_sums(const int* __restrict__ cnt, int* __restrict__ bsum, int n) {
  __shared__ int s[256];
  int i = blockIdx.x * 256 + threadIdx.x;
  s[threadIdx.x] = (i < n) ? cnt[i] : 0;
  __syncthreads();
  for (int st = 128; st > 0; st >>= 1) {
    if ((int)threadIdx.x < st) s[threadIdx.x] += s[threadIdx.x + st];
    __syncthreads();
  }
  if (threadIdx.x == 0) bsum[blockIdx.x] = s[0];
}

__global__ __launch_bounds__(1024) void scan_partials(int* __restrict__ bsum, int nb) {
  __shared__ int s[1024];
  int v = ((int)threadIdx.x < nb) ? bsum[threadIdx.x] : 0;
  s[threadIdx.x] = v;
  __syncthreads();
  for (int st = 1; st < 1024; st <<= 1) {
    int t = ((int)threadIdx.x >= st) ? s[threadIdx.x - st] : 0;
    __syncthreads();
    s[threadIdx.x] += t;
    __syncthreads();
  }
  if ((int)threadIdx.x < nb) bsum[threadIdx.x] = s[threadIdx.x] - v;  // exclusive
}

__global__ __launch_bounds__(256) void write_rowptr(
    const int* __restrict__ cnt, const int* __restrict__ bsum,
    int* __restrict__ rowptr, int* __restrict__ wp, int n, int total) {
  __shared__ int s[256];
  int i = blockIdx.x * 256 + threadIdx.x;
  int v = (i < n) ? cnt[i] : 0;
  s[threadIdx.x] = v;
  __syncthreads();
  for (int st = 1; st < 256; st <<= 1) {
    int t = ((int)threadIdx.x >= st) ? s[threadIdx.x - st] : 0;
    __syncthreads();
    s[threadIdx.x] += t;
    __syncthreads();
  }
  int excl = s[threadIdx.x] - v + bsum[blockIdx.x];
  if (i < n) { rowptr[i] = excl; wp[i] = excl; }
  if (i == n - 1) rowptr[n] = total;
}

// 1 edge/thread (4/thread regressed: occupancy 74->45%, dur 128->145us).
// Breakpoints staged in LDS; unrolled 32-compare replaces the dependent
// global binary search.
__global__ __launch_bounds__(256) void csr_fill_dual(
    const int* __restrict__ src_s, const int* __restrict__ dst_s, const float* __restrict__ attr_s,
    const int* __restrict__ src_g, const int* __restrict__ dst_g, const float* __restrict__ attr_g,
    const float* __restrict__ tabs, int* __restrict__ wp, int2* __restrict__ colattr) {
  __shared__ float bp[32];
  if (threadIdx.x < 32) bp[threadIdx.x] = tabs[TAB_BP + threadIdx.x];
  __syncthreads();
  int half = blockIdx.x >= EBLK;
  int e = (blockIdx.x - half * EBLK) * 256 + threadIdx.x;  // exact
  int sl, d;
  float a;
  if (half) { sl = src_g[e]; d = dst_g[e] + NN; a = attr_g[e]; }
  else      { sl = src_s[e]; d = dst_s[e];      a = attr_s[e]; }
  int g = 0;  // seg = #(bp < a)
#pragma unroll
  for (int i = 0; i < 32; ++i) g += (bp[i] < a);
  int pos = atomicAdd(&wp[d], 1);
  colattr[pos] = make_int2(sl | (g << 20), __float_as_int(a));  // src<2^17, seg<64
}

// ---------------------------------------------------------------------------
// GINE aggregation, dst-major. One WAVE per node; a wave processes several
// edges concurrently (sub = edge slot, fq = float4 feature chunk) so 8-16 row
// gathers are in flight per wave (latency-bound fix).
// hb[n] = x[n] + sum_j relu(x[src_j] + e_j)
// rowptr is pre-offset per graph (rowptr + half*NN); colattr positions are
// global across both graphs; src ids in colattr are graph-local.
// ---------------------------------------------------------------------------
__global__ __launch_bounds__(256) void conv1_agg(
    const float* __restrict__ x0, const int* __restrict__ rowptr,
    const int2* __restrict__ colattr, const float* __restrict__ tabs,
    float* __restrict__ hb) {
  __shared__ float dt[NSEG * 32];
  __shared__ float ct[NSEG * 32];
  for (int i = threadIdx.x; i < NSEG * 32; i += 256) {
    dt[i] = tabs[TAB_D1 + i];
    ct[i] = tabs[TAB_C1 + i];
  }
  __syncthreads();
  int n = blockIdx.x * 4 + (threadIdx.x >> 6);  // grid exact: NN/4
  int lane = threadIdx.x & 63;
  int sub = lane & 7;        // 8 edges in flight (x2 unroll = 16)
  int fq  = lane >> 3;       // 8 float4 chunks -> 32 features
  int f0  = fq * 4;
  int beg = rowptr[n], end = rowptr[n + 1];
  float4 acc = make_float4(0.f, 0.f, 0.f, 0.f);
  for (int k = beg + sub; k < end; k += 16) {
    int2 ca0 = colattr[k];
    int kb = k + 8;
    bool h1 = kb < end;
    int2 ca1 = h1 ? colattr[kb] : ca0;
    unsigned p0 = (unsigned)ca0.x, p1 = (unsigned)ca1.x;
    int s0 = (int)(p0 & 0xFFFFFu), g0 = (int)(p0 >> 20);
    int s1 = (int)(p1 & 0xFFFFFu), g1 = (int)(p1 >> 20);
    float a0 = __int_as_float(ca0.y), a1 = __int_as_float(ca1.y);
    float4 xv0 = *(const float4*)(x0 + (size_t)s0 * 32 + f0);
    float4 xv1 = *(const float4*)(x0 + (size_t)s1 * 32 + f0);
    float4 d0 = *(const float4*)&dt[g0 * 32 + f0];
    float4 c0 = *(const float4*)&ct[g0 * 32 + f0];
    float4 d1 = *(const float4*)&dt[g1 * 32 + f0];
    float4 c1 = *(const float4*)&ct[g1 * 32 + f0];
    acc.x += relu_(xv0.x + fmaf(a0, d0.x, c0.x));
    acc.y += relu_(xv0.y + fmaf(a0, d0.y, c0.y));
    acc.z += relu_(xv0.z + fmaf(a0, d0.z, c0.z));
    acc.w += relu_(xv0.w + fmaf(a0, d0.w, c0.w));
    if (h1) {
      acc.x += relu_(xv1.x + fmaf(a1, d1.x, c1.x));
      acc.y += relu_(xv1.y + fmaf(a1, d1.y, c1.y));
      acc.z += relu_(xv1.z + fmaf(a1, d1.z, c1.z));
      acc.w += relu_(xv1.w + fmaf(a1, d1.w, c1.w));
    }
  }
#pragma unroll
  for (int m = 1; m < 8; m <<= 1) {
    float4 o = shfl_xor4(acc, m);
    acc.x += o.x; acc.y += o.y; acc.z += o.z; acc.w += o.w;
  }
  if (sub == 0) {
    const float4 self = *(const float4*)(x0 + (size_t)n * 32 + f0);
    *(float4*)(hb + (size_t)n * 32 + f0) =
        make_float4(self.x + acc.x, self.y + acc.y, self.z + acc.z, self.w + acc.w);
  }
}

__global__ __launch_bounds__(256) void conv2_agg(
    const float* __restrict__ x1, const int* __restrict__ rowptr,
    const int2* __restrict__ colattr, const float* __restrict__ tabs, int enc,
    float* __restrict__ hb) {
  __shared__ float dt[NSEG * 64];
  __shared__ float ct[NSEG * 64];
  const float* d2 = tabs + TAB_E2 + (size_t)enc * 2 * NSEG * 64;
  for (int i = threadIdx.x; i < NSEG * 64; i += 256) {
    dt[i] = d2[i];
    ct[i] = d2[NSEG * 64 + i];
  }
  __syncthreads();
  int n = blockIdx.x * 4 + (threadIdx.x >> 6);  // grid exact: NN/4
  int lane = threadIdx.x & 63;
  int sub = lane & 3;        // 4 edges in flight (x2 unroll = 8)
  int fq  = lane >> 2;       // 16 float4 chunks -> 64 features
  int f0  = fq * 4;
  int beg = rowptr[n], end = rowptr[n + 1];
  float4 acc = make_float4(0.f, 0.f, 0.f, 0.f);
  for (int k = beg + sub; k < end; k += 8) {
    int2 ca0 = colattr[k];
    int kb = k + 4;
    bool h1 = kb < end;
    int2 ca1 = h1 ? colattr[kb] : ca0;
    unsigned p0 = (unsigned)ca0.x, p1 = (unsigned)ca1.x;
    int s0 = (int)(p0 & 0xFFFFFu), g0 = (int)(p0 >> 20);
    int s1 = (int)(p1 & 0xFFFFFu), g1 = (int)(p1 >> 20);
    float a0 = __int_as_float(ca0.y), a1 = __int_as_float(ca1.y);
    float4 xv0 = *(const float4*)(x1 + (size_t)s0 * 64 + f0);
    float4 xv1 = *(const float4*)(x1 + (size_t)s1 * 64 + f0);
    float4 d0 = *(const float4*)&dt[g0 * 64 + f0];
    float4 c0 = *(const float4*)&ct[g0 * 64 + f0];
    float4 d1 = *(const float4*)&dt[g1 * 64 + f0];
    float4 c1 = *(const float4*)&ct[g1 * 64 + f0];
    acc.x += relu_(xv0.x + fmaf(a0, d0.x, c0.x));
    acc.y += relu_(xv0.y + fmaf(a0, d0.y, c0.y));
    acc.z += relu_(xv0.z + fmaf(a0, d0.z, c0.z));
    acc.w += relu_(xv0.w + fmaf(a0, d0.w, c0.w));
    if (h1) {
      acc.x += relu_(xv1.x + fmaf(a1, d1.x, c1.x));
      acc.y += relu_(xv1.y + fmaf(a1, d1.y, c1.y));
      acc.z += relu_(xv1.z + fmaf(a1, d1.z, c1.z));
      acc.w += relu_(xv1.w + fmaf(a1, d1.w, c1.w));
    }
  }
#pragma unroll
  for (int m = 1; m < 4; m <<= 1) {
    float4 o = shfl_xor4(acc, m);
    acc.x += o.x; acc.y += o.y; acc.z += o.z; acc.w += o.w;
  }
  if (sub == 0) {
    const float4 self = *(const float4*)(x1 + (size_t)n * 64 + f0);
    *(float4*)(hb + (size_t)n * 64 + f0) =
        make_float4(self.x + acc.x, self.y + acc.y, self.z + acc.z, self.w + acc.w);
  }
}

// ---------------------------------------------------------------------------
// Per-node MLP2 (IN -> 64 -> 64), relu on output (conv wrapper relu).
// __launch_bounds__(TPB, 2): min 2 waves/EU -> 256-VGPR budget so y[64]
// stays in registers. (Without the 2nd arg the backend capped VGPRs at ~52
// and spilled y[64] to scratch -- observed round 3.)
// ---------------------------------------------------------------------------
template <int IN, int TPB>
__global__ __launch_bounds__(TPB, 2) void node_mlp(
    const float* __restrict__ hin,
    const float* __restrict__ W1, const float* __restrict__ b1,
    const float* __restrict__ W2, const float* __restrict__ b2,
    float* __restrict__ xout) {
  __shared__ float hs[TPB][IN + 1];
  int base = blockIdx.x * TPB;
  int count = NN - base; if (count > TPB) count = TPB;
  for (int i = threadIdx.x; i < count * IN; i += TPB) {
    int ln = i / IN, k = i - ln * IN;
    hs[ln][k] = hin[(size_t)(base + ln) * IN + k];
  }
  __syncthreads();
  int n = base + threadIdx.x;
  if (n >= NN) return;
  float y[64];
#pragma unroll
  for (int f = 0; f < 64; ++f) y[f] = b1[f];
  for (int k = 0; k < IN; ++k) {
    float hv = hs[threadIdx.x][k];
#pragma unroll
    for (int f = 0; f < 64; ++f) y[f] = fmaf(hv, W1[k * 64 + f], y[f]);
  }
#pragma unroll
  for (int f = 0; f < 64; ++f) y[f] = relu_(y[f]);
  float4* out = (float4*)(xout + (size_t)n * 64);
  for (int f0 = 0; f0 < 64; f0 += 4) {
    float a0 = b2[f0], a1 = b2[f0 + 1], a2 = b2[f0 + 2], a3 = b2[f0 + 3];
#pragma unroll
    for (int k = 0; k < 64; ++k) {
      float yv = y[k];
      a0 = fmaf(yv, W2[k * 64 + f0],     a0);
      a1 = fmaf(yv, W2[k * 64 + f0 + 1], a1);
      a2 = fmaf(yv, W2[k * 64 + f0 + 2], a2);
      a3 = fmaf(yv, W2[k * 64 + f0 + 3], a3);
    }
    out[f0 >> 2] = make_float4(relu_(a0), relu_(a1), relu_(a2), relu_(a3));
  }
}

// ---------------------------------------------------------------------------
// global mean pool (batch is sorted -> contiguous node ranges per graph)
// ---------------------------------------------------------------------------
__global__ __launch_bounds__(256) void hist_batch(const int* __restrict__ bat, int* __restrict__ bcnt) {
  int i = blockIdx.x * 256 + threadIdx.x;
  if (i < NN) atomicAdd(&bcnt[bat[i]], 1);
}

__global__ __launch_bounds__(512) void batch_rowptr(const int* __restrict__ bcnt, int* __restrict__ brow) {
  __shared__ int s[512];
  int v = bcnt[threadIdx.x];
  s[threadIdx.x] = v;
  __syncthreads();
  for (int st = 1; st < 512; st <<= 1) {
    int t = ((int)threadIdx.x >= st) ? s[threadIdx.x - st] : 0;
    __syncthreads();
    s[threadIdx.x] += t;
    __syncthreads();
  }
  if (threadIdx.x == 0) brow[0] = 0;
  brow[threadIdx.x + 1] = s[threadIdx.x];
}

__global__ __launch_bounds__(256) void pool_mean(
    const float* __restrict__ x2, const int* __restrict__ brow, float* __restrict__ pool) {
  __shared__ float s[4][64];
  int g = blockIdx.x;
  int f = threadIdx.x & 63, c = threadIdx.x >> 6;
  int beg = brow[g], end = brow[g + 1];
  float acc = 0.0f;
  for (int n = beg + c; n < end; n += 4) acc += x2[(size_t)n * 64 + f];
  s[c][f] = acc;
  __syncthreads();
  if (c == 0) {
    float tot = s[0][f] + s[1][f] + s[2][f] + s[3][f];
    float m = (float)(end - beg);
    pool[g * 64 + f] = tot / fmaxf(m, 1.0f);
  }
}

// ---------------------------------------------------------------------------
// regressor: out[b] = relu([s|g|depth] @ rW1 + rb1) @ rW2 + rb2
// ---------------------------------------------------------------------------
__global__ __launch_bounds__(256, 2) void regressor(
    const float* __restrict__ ps, const float* __restrict__ pg, const float* __restrict__ depth,
    const float* __restrict__ W1, const float* __restrict__ b1,
    const float* __restrict__ W2, const float* __restrict__ b2,
    float* __restrict__ out) {
  int b = blockIdx.x * 256 + threadIdx.x;  // grid 2x256 = 512 exact
  float y[64];
#pragma unroll
  for (int f = 0; f < 64; ++f) y[f] = b1[f];
  for (int k = 0; k < 64; ++k) {
    float zv = ps[(size_t)b * 64 + k];
#pragma unroll
    for (int f = 0; f < 64; ++f) y[f] = fmaf(zv, W1[k * 64 + f], y[f]);
  }
  for (int k = 0; k < 64; ++k) {
    float zv = pg[(size_t)b * 64 + k];
#pragma unroll
    for (int f = 0; f < 64; ++f) y[f] = fmaf(zv, W1[(64 + k) * 64 + f], y[f]);
  }
  {
    float zv = depth[b];
#pragma unroll
    for (int f = 0; f < 64; ++f) y[f] = fmaf(zv, W1[128 * 64 + f], y[f]);
  }
  float acc = b2[0];
#pragma unroll
  for (int f = 0; f < 64; ++f) acc = fmaf(relu_(y[f]), W2[f], acc);
  out[b] = acc;
}

}  // namespace

extern "C" void kernel_launch(void* const* d_in, const int* in_sizes, int n_in,
                              void* d_out, int out_size, void* d_ws, size_t ws_size,
                              hipStream_t stream) {
  const int*   names_s = (const int*)d_in[0];
  const int*   ei_s    = (const int*)d_in[1];
  const float* ea_s    = (const float*)d_in[2];
  const int*   bat_s   = (const int*)d_in[3];
  const int*   names_g = (const int*)d_in[4];
  const int*   ei_g    = (const int*)d_in[5];
  const float* ea_g    = (const float*)d_in[6];
  const int*   bat_g   = (const int*)d_in[7];
  const float* depth   = (const float*)d_in[8];
  const float* idW1 = (const float*)d_in[9],  *idb1 = (const float*)d_in[10];
  const float* idW2 = (const float*)d_in[11], *idb2 = (const float*)d_in[12];
  const float* edW1 = (const float*)d_in[13], *edb1 = (const float*)d_in[14];
  const float* edW2 = (const float*)d_in[15], *edb2 = (const float*)d_in[16];
  const float* s1W1 = (const float*)d_in[17], *s1b1 = (const float*)d_in[18];
  const float* s1W2 = (const float*)d_in[19], *s1b2 = (const float*)d_in[20];
  const float* s2W1 = (const float*)d_in[21], *s2b1 = (const float*)d_in[22];
  const float* s2W2 = (const float*)d_in[23], *s2b2 = (const float*)d_in[24];
  const float* s2LW = (const float*)d_in[25], *s2Lb = (const float*)d_in[26];
  const float* g1W1 = (const float*)d_in[27], *g1b1 = (const float*)d_in[28];
  const float* g1W2 = (const float*)d_in[29], *g1b2 = (const float*)d_in[30];
  const float* g2W1 = (const float*)d_in[31], *g2b1 = (const float*)d_in[32];
  const float* g2W2 = (const float*)d_in[33], *g2b2 = (const float*)d_in[34];
  const float* g2LW = (const float*)d_in[35], *g2Lb = (const float*)d_in[36];
  const float* rW1  = (const float*)d_in[37], *rb1  = (const float*)d_in[38];
  const float* rW2  = (const float*)d_in[39], *rb2  = (const float*)d_in[40];
  (void)in_sizes; (void)n_in; (void)out_size; (void)ws_size;

  char* ws = (char*)d_ws;
  size_t off = 0;
  auto alloc = [&](size_t bytes) -> char* {
    char* p = ws + off;
    off += (bytes + 255) & ~(size_t)255;
    return p;
  };
  float* tabs    = (float*)alloc((size_t)TAB_TOTAL * 4);
  float* bufA    = (float*)alloc((size_t)NN * 64 * 4);       // per-graph x0 -> x1 -> x2
  float* bufB    = (float*)alloc((size_t)NN * 64 * 4);       // per-graph h1 -> h2
  int2*  colattr = (int2*) alloc((size_t)2 * NEDG * 8);      // both graphs
  int*   cnt     = (int*)  alloc((size_t)2 * NN * 4);
  int*   rowptr  = (int*)  alloc((size_t)(2 * NN + 1) * 4);
  int*   wp      = (int*)  alloc((size_t)2 * NN * 4);
  int*   bsum    = (int*)  alloc(1024 * 4);
  int*   bcnt    = (int*)  alloc((size_t)NBAT * 4);
  int*   brow    = (int*)  alloc((size_t)(NBAT + 1) * 4);
  float* pool_s  = (float*)alloc((size_t)NBAT * 64 * 4);
  float* pool_g  = (float*)alloc((size_t)NBAT * 64 * 4);

  const int NB2 = (2 * NN + 255) / 256;  // 782 blocks over both graphs' nodes

  build_tables<<<1, 256, 0, stream>>>(edW1, edb1, edW2, edb2, s2LW, s2Lb, g2LW, g2Lb, tabs);

  // --- merged CSR build for BOTH graphs (one latency-bound pass, 2x parallelism)
  hipMemsetAsync(cnt, 0, (size_t)2 * NN * 4, stream);
  hist_dst_dual<<<2 * EBLK, 256, 0, stream>>>(ei_s + NEDG, ei_g + NEDG, cnt);
  block_sums<<<NB2, 256, 0, stream>>>(cnt, bsum, 2 * NN);
  scan_partials<<<1, 1024, 0, stream>>>(bsum, NB2);
  write_rowptr<<<NB2, 256, 0, stream>>>(cnt, bsum, rowptr, wp, 2 * NN, 2 * NEDG);
  csr_fill_dual<<<2 * EBLK, 256, 0, stream>>>(ei_s, ei_s + NEDG, ea_s,
                                              ei_g, ei_g + NEDG, ea_g,
                                              tabs, wp, colattr);

  auto encoder = [&](const int* names, const int* bat, const int* rp,
                     const float* c1W1, const float* c1b1, const float* c1W2, const float* c1b2,
                     const float* c2W1, const float* c2b1, const float* c2W2, const float* c2b2,
                     int enc, float* pool) {
    node_embed<<<391, 256, 0, stream>>>(names, idW1, idb1, idW2, idb2, bufA);
    conv1_agg<<<NN / 4, 256, 0, stream>>>(bufA, rp, colattr, tabs, bufB);
    node_mlp<32, 256><<<(NN + 255) / 256, 256, 0, stream>>>(bufB, c1W1, c1b1, c1W2, c1b2, bufA);
    conv2_agg<<<NN / 4, 256, 0, stream>>>(bufA, rp, colattr, tabs, enc, bufB);
    node_mlp<64, 128><<<(NN + 127) / 128, 128, 0, stream>>>(bufB, c2W1, c2b1, c2W2, c2b2, bufA);
    hipMemsetAsync(bcnt, 0, (size_t)NBAT * 4, stream);
    hist_batch<<<391, 256, 0, stream>>>(bat, bcnt);
    batch_rowptr<<<1, 512, 0, stream>>>(bcnt, brow);
    pool_mean<<<NBAT, 256, 0, stream>>>(bufA, brow, pool);
  };

  encoder(names_s, bat_s, rowptr,      s1W1, s1b1, s1W2, s1b2, s2W1, s2b1, s2W2, s2b2, 0, pool_s);
  encoder(names_g, bat_g, rowptr + NN, g1W1, g1b1, g1W2, g1b2, g2W1, g2b1, g2W2, g2b2, 1, pool_g);

  regressor<<<2, 256, 0, stream>>>(pool_s, pool_g, depth, rW1, rb1, rW2, rb2, (float*)d_out);
}